// Round 1
// baseline (265.553 us; speedup 1.0000x reference)
//
#include <hip/hip_runtime.h>
#include <hip/hip_bf16.h>
#include <stdint.h>

typedef __bf16 bf16_t;
typedef __bf16 bf16x8 __attribute__((ext_vector_type(8)));
typedef float f32x4 __attribute__((ext_vector_type(4)));
typedef unsigned short ushortx8 __attribute__((ext_vector_type(8)));

#define SEQ_LEN 4096
#define D_MODEL 1024
#define N_HEAD 16

// ---------- helpers ----------

__device__ __forceinline__ void gload_lds16(const void* g, void* lds) {
  __builtin_amdgcn_global_load_lds(
      (__attribute__((address_space(1))) void*)(g),
      (__attribute__((address_space(3))) void*)(lds), 16, 0, 0);
}

__device__ __forceinline__ unsigned short f2bfu(float f) {
  __bf16 h = (__bf16)f;
  return __builtin_bit_cast(unsigned short, h);
}

// XOR-swizzled LDS frag read: base is a [64 rows][64 bf16] tile, rows = 128B.
// byte = (row*128 + chunk*16) ^ ((row&7)<<4)
__device__ __forceinline__ bf16x8 lds_frag(const bf16_t* base, int row, int chunk) {
  int off = (row * 128 + chunk * 16) ^ ((row & 7) << 4);
  return *(const bf16x8*)((const char*)base + off);
}

// ---------- conversion kernels ----------

__global__ __launch_bounds__(256) void cvt_f32_bf16(const float* __restrict__ in,
                                                    bf16_t* __restrict__ out, int n) {
  int i = (blockIdx.x * 256 + threadIdx.x) * 4;
  if (i < n) {
    float4 v = *(const float4*)(in + i);
    unsigned int lo = (unsigned)f2bfu(v.x) | ((unsigned)f2bfu(v.y) << 16);
    unsigned int hi = (unsigned)f2bfu(v.z) | ((unsigned)f2bfu(v.w) << 16);
    uint2 pk; pk.x = lo; pk.y = hi;
    *(uint2*)(out + i) = pk;
  }
}

// W[R][C] f32 -> Wt[C][R] bf16, 64x64 tiles through LDS (both sides coalesced)
__global__ __launch_bounds__(256) void transpose_cvt(const float* __restrict__ W,
                                                     bf16_t* __restrict__ Wt,
                                                     int R, int C) {
  __shared__ float tile[64][65];
  const int tc = C >> 6;
  const int bc = blockIdx.x % tc;
  const int br = blockIdx.x / tc;
  #pragma unroll
  for (int p = 0; p < 16; ++p) {
    int idx = p * 256 + threadIdx.x;
    int i = idx >> 6, j = idx & 63;
    tile[i][j] = W[(size_t)(br * 64 + i) * C + bc * 64 + j];
  }
  __syncthreads();
  #pragma unroll
  for (int p = 0; p < 16; ++p) {
    int idx = p * 256 + threadIdx.x;
    int jj = idx >> 6, ii = idx & 63;
    Wt[(size_t)(bc * 64 + jj) * R + br * 64 + ii] = (bf16_t)tile[ii][jj];
  }
}

// ---------- GEMM: C[M][N] = A[M][K] * Bt[N][K]^T + bias ----------
// m97 structure: 128x128 tile, BK=32, 4 waves (2x2), 4x4 frags of 16x16x32.

template <bool OUT_BF16>
__global__ __launch_bounds__(256) void gemm_bt(const bf16_t* __restrict__ A,
                                               const bf16_t* __restrict__ Bt,
                                               const float* __restrict__ bias,
                                               void* __restrict__ Cout,
                                               int M, int N, int K) {
  __shared__ bf16_t As[128 * 32];
  __shared__ bf16_t Bs[128 * 32];
  const int tid = threadIdx.x;
  const int lane = tid & 63;
  const int w = tid >> 6;
  const int wr = (w >> 1) * 64;
  const int wc = (w & 1) * 64;
  const int i16 = lane & 15;
  const int g = lane >> 4;
  const int ntn = N >> 7;
  const int bm = blockIdx.x / ntn;
  const int bn = blockIdx.x % ntn;
  const bf16_t* Abase = A + (size_t)(bm * 128) * K;
  const bf16_t* Bbase = Bt + (size_t)(bn * 128) * K;

  f32x4 acc[4][4];
  #pragma unroll
  for (int m = 0; m < 4; ++m)
    #pragma unroll
    for (int n = 0; n < 4; ++n)
      acc[m][n] = (f32x4){0.f, 0.f, 0.f, 0.f};

  for (int kt = 0; kt < K; kt += 32) {
    __syncthreads();
    #pragma unroll
    for (int p = 0; p < 2; ++p) {
      int idx = p * 256 + tid;
      int row = idx >> 2, ch = idx & 3;
      gload_lds16(Abase + (size_t)row * K + kt + ch * 8, (char*)As + idx * 16);
      gload_lds16(Bbase + (size_t)row * K + kt + ch * 8, (char*)Bs + idx * 16);
    }
    __syncthreads();
    bf16x8 af[4], bq[4];
    #pragma unroll
    for (int m = 0; m < 4; ++m)
      af[m] = *(const bf16x8*)(As + (wr + m * 16 + i16) * 32 + g * 8);
    #pragma unroll
    for (int n = 0; n < 4; ++n)
      bq[n] = *(const bf16x8*)(Bs + (wc + n * 16 + i16) * 32 + g * 8);
    #pragma unroll
    for (int m = 0; m < 4; ++m)
      #pragma unroll
      for (int n = 0; n < 4; ++n)
        acc[m][n] = __builtin_amdgcn_mfma_f32_16x16x32_bf16(af[m], bq[n], acc[m][n], 0, 0, 0);
  }

  // epilogue: C/D layout col=lane&15, row=(lane>>4)*4+reg  (m89-verified)
  #pragma unroll
  for (int m = 0; m < 4; ++m) {
    #pragma unroll
    for (int n = 0; n < 4; ++n) {
      int col = bn * 128 + wc + n * 16 + i16;
      float bv = bias ? bias[col] : 0.f;
      #pragma unroll
      for (int r = 0; r < 4; ++r) {
        int row = bm * 128 + wr + m * 16 + g * 4 + r;
        float v = acc[m][n][r] + bv;
        if (OUT_BF16)
          ((bf16_t*)Cout)[(size_t)row * N + col] = (bf16_t)v;
        else
          ((float*)Cout)[(size_t)row * N + col] = v;
      }
    }
  }
}

// ---------- causal flash attention ----------
// Block = (head, 64 q rows). 4 waves x 16 q rows. KV-tile = 64.
// Swapped QK^T: S^T = mfma(K, Q) -> lane holds keys for q = lane&15.
// PV as O^T = mfma(V^T, P^T).

__global__ __launch_bounds__(256) void attn_fwd(const bf16_t* __restrict__ qkv,
                                                bf16_t* __restrict__ aout) {
  __shared__ bf16_t Ks[64 * 64];
  __shared__ bf16_t Vt[64 * 64];
  const int tid = threadIdx.x;
  const int lane = tid & 63;
  const int w = tid >> 6;
  const int i16 = lane & 15;
  const int g = lane >> 4;
  const int h = blockIdx.x & 15;
  const int qb = 63 - (blockIdx.x >> 4);   // heaviest blocks dispatched first
  const int qg = qb * 64 + w * 16 + i16;   // this lane's q row

  // Q fragments (B-operand: lane holds Q[q=i16][dh chunk])
  bf16x8 qf[2];
  #pragma unroll
  for (int kk = 0; kk < 2; ++kk)
    qf[kk] = *(const bf16x8*)(qkv + (size_t)qg * 3072 + h * 64 + kk * 32 + g * 8);

  f32x4 ot[4];
  #pragma unroll
  for (int md = 0; md < 4; ++md) ot[md] = (f32x4){0.f, 0.f, 0.f, 0.f};
  float m_run = -1e30f, l_run = 0.f;
  const float sc = 0.18033688011112042f;  // log2(e)/sqrt(64)

  const int ntiles = qb + 1;
  for (int t = 0; t < ntiles; ++t) {
    const int kv = t * 64;
    __syncthreads();
    // stage K tile [64 keys][64 dh], XOR-swizzled rows
    #pragma unroll
    for (int p = 0; p < 2; ++p) {
      int idx = p * 256 + tid;
      int key = idx >> 3, ch = idx & 7;
      uint4 d = *(const uint4*)(qkv + (size_t)(kv + key) * 3072 + 1024 + h * 64 + ch * 8);
      int off = (key * 128 + ch * 16) ^ ((key & 7) << 4);
      *(uint4*)((char*)Ks + off) = d;
    }
    // stage V^T tile [64 dh][64 keys], transposed + XOR-swizzled
    {
      int kp = tid >> 3;
      int dh0 = (tid & 7) * 8;
      const bf16_t* vp = qkv + (size_t)(kv + 2 * kp) * 3072 + 2048 + h * 64 + dh0;
      ushortx8 a = *(const ushortx8*)vp;
      ushortx8 b = *(const ushortx8*)(vp + 3072);
      #pragma unroll
      for (int j = 0; j < 8; ++j) {
        unsigned int pk = (unsigned int)a[j] | ((unsigned int)b[j] << 16);
        int dh = dh0 + j;
        int off = (dh * 128 + kp * 4) ^ ((dh & 7) << 4);
        *(unsigned int*)((char*)Vt + off) = pk;
      }
    }
    __syncthreads();

    // S^T = K . Q^T ; lane: key = m*16 + g*4 + r, q = i16
    float sv[4][4];
    float tmax = -1e30f;
    const bool masked = (t == qb);
    #pragma unroll
    for (int m = 0; m < 4; ++m) {
      f32x4 z = (f32x4){0.f, 0.f, 0.f, 0.f};
      #pragma unroll
      for (int kk = 0; kk < 2; ++kk) {
        bf16x8 kf = lds_frag(Ks, m * 16 + i16, kk * 4 + g);
        z = __builtin_amdgcn_mfma_f32_16x16x32_bf16(kf, qf[kk], z, 0, 0, 0);
      }
      #pragma unroll
      for (int r = 0; r < 4; ++r) {
        float x = z[r] * sc;
        if (masked) {
          int key = kv + m * 16 + g * 4 + r;
          if (key > qg) x = -1e30f;
        }
        sv[m][r] = x;
        tmax = fmaxf(tmax, x);
      }
    }
    tmax = fmaxf(tmax, __shfl_xor(tmax, 16));
    tmax = fmaxf(tmax, __shfl_xor(tmax, 32));
    float mnew = fmaxf(m_run, tmax);
    float alpha = exp2f(m_run - mnew);
    m_run = mnew;

    float pv[4][4];
    float rsum = 0.f;
    #pragma unroll
    for (int m = 0; m < 4; ++m)
      #pragma unroll
      for (int r = 0; r < 4; ++r) {
        pv[m][r] = exp2f(sv[m][r] - mnew);
        rsum += pv[m][r];
      }
    rsum += __shfl_xor(rsum, 16);
    rsum += __shfl_xor(rsum, 32);
    l_run = l_run * alpha + rsum;
    #pragma unroll
    for (int md = 0; md < 4; ++md)
      #pragma unroll
      for (int r = 0; r < 4; ++r) ot[md][r] *= alpha;

    // P^T -> B-frag layout: lane needs key_t = kk*32 + g*8 + j, q = i16.
    // source: reg (m_s = kk*2 + (g>>1), r_s = j&3), lane = ((g&1)*2 + (j>>2))*16 + i16
    bf16x8 pfb[2];
    #pragma unroll
    for (int kk = 0; kk < 2; ++kk) {
      float vals[8];
      #pragma unroll
      for (int j = 0; j < 8; ++j) {
        int src = ((g & 1) * 2 + (j >> 2)) * 16 + i16;
        float vA = __shfl(pv[kk * 2][j & 3], src);
        float vB = __shfl(pv[kk * 2 + 1][j & 3], src);
        vals[j] = (g >= 2) ? vB : vA;
      }
      bf16x8 pf;
      #pragma unroll
      for (int j = 0; j < 8; ++j) pf[j] = (bf16_t)vals[j];
      pfb[kk] = pf;
    }

    // O^T += V^T . P^T
    #pragma unroll
    for (int md = 0; md < 4; ++md)
      #pragma unroll
      for (int kk = 0; kk < 2; ++kk) {
        bf16x8 vf = lds_frag(Vt, md * 16 + i16, kk * 4 + g);
        ot[md] = __builtin_amdgcn_mfma_f32_16x16x32_bf16(vf, pfb[kk], ot[md], 0, 0, 0);
      }
  }

  // epilogue: lane writes q-row qg, dh = md*16 + g*4 + r (4 contiguous bf16 per store)
  float inv = 1.0f / l_run;
  #pragma unroll
  for (int md = 0; md < 4; ++md) {
    unsigned int lo = (unsigned)f2bfu(ot[md][0] * inv) | ((unsigned)f2bfu(ot[md][1] * inv) << 16);
    unsigned int hi = (unsigned)f2bfu(ot[md][2] * inv) | ((unsigned)f2bfu(ot[md][3] * inv) << 16);
    int col = h * 64 + md * 16 + g * 4;
    uint2 pk; pk.x = lo; pk.y = hi;
    *(uint2*)(aout + (size_t)qg * 1024 + col) = pk;
  }
}

// ---------- launch ----------

extern "C" void kernel_launch(void* const* d_in, const int* in_sizes, int n_in,
                              void* d_out, int out_size, void* d_ws, size_t ws_size,
                              hipStream_t stream) {
  const float* x     = (const float*)d_in[0];
  const float* w_qkv = (const float*)d_in[1];
  const float* b_qkv = (const float*)d_in[2];
  const float* w_o   = (const float*)d_in[3];
  const float* b_o   = (const float*)d_in[4];

  char* ws = (char*)d_ws;
  bf16_t* xh    = (bf16_t*)(ws);                          //  8 MiB
  bf16_t* wqkvT = (bf16_t*)(ws + 8388608);                //  6 MiB
  bf16_t* woT   = (bf16_t*)(ws + 14680064);               //  2 MiB
  bf16_t* qkv   = (bf16_t*)(ws + 16777216);               // 24 MiB
  bf16_t* aout  = (bf16_t*)(ws + 41943040);               //  8 MiB

  cvt_f32_bf16<<<(SEQ_LEN * D_MODEL) / 1024, 256, 0, stream>>>(x, xh, SEQ_LEN * D_MODEL);
  transpose_cvt<<<(1024 / 64) * (3072 / 64), 256, 0, stream>>>(w_qkv, wqkvT, 1024, 3072);
  transpose_cvt<<<(1024 / 64) * (1024 / 64), 256, 0, stream>>>(w_o, woT, 1024, 1024);

  gemm_bt<true><<<(4096 / 128) * (3072 / 128), 256, 0, stream>>>(
      xh, wqkvT, b_qkv, (void*)qkv, 4096, 3072, 1024);

  attn_fwd<<<N_HEAD * (SEQ_LEN / 64), 256, 0, stream>>>(qkv, aout);

  gemm_bt<false><<<(4096 / 128) * (1024 / 128), 256, 0, stream>>>(
      aout, woT, b_o, d_out, 4096, 1024, 1024);
}

// Round 2
// 193.030 us; speedup vs baseline: 1.3757x; 1.3757x over previous
//
#include <hip/hip_runtime.h>
#include <hip/hip_bf16.h>
#include <stdint.h>

typedef __bf16 bf16_t;
typedef __bf16 bf16x8 __attribute__((ext_vector_type(8)));
typedef float f32x4 __attribute__((ext_vector_type(4)));
typedef float f32x16 __attribute__((ext_vector_type(16)));
typedef unsigned short ushortx8 __attribute__((ext_vector_type(8)));

#define SEQ_LEN 4096
#define D_MODEL 1024
#define N_HEAD 16

// ---------- helpers ----------

__device__ __forceinline__ void gload_lds16(const void* g, void* lds) {
  __builtin_amdgcn_global_load_lds(
      (__attribute__((address_space(1))) void*)(g),
      (__attribute__((address_space(3))) void*)(lds), 16, 0, 0);
}

__device__ __forceinline__ unsigned short f2bfu(float f) {
  __bf16 h = (__bf16)f;
  return __builtin_bit_cast(unsigned short, h);
}

__device__ __forceinline__ unsigned cvt_pk_bf16(float a, float b) {
  unsigned r;
  asm("v_cvt_pk_bf16_f32 %0, %1, %2" : "=v"(r) : "v"(a), "v"(b));
  return r;  // lo = bf16(a), hi = bf16(b)
}

// ---------- conversion kernels ----------

__global__ __launch_bounds__(256) void cvt_f32_bf16(const float* __restrict__ in,
                                                    bf16_t* __restrict__ out, int n) {
  int i = (blockIdx.x * 256 + threadIdx.x) * 4;
  if (i < n) {
    float4 v = *(const float4*)(in + i);
    unsigned int lo = (unsigned)f2bfu(v.x) | ((unsigned)f2bfu(v.y) << 16);
    unsigned int hi = (unsigned)f2bfu(v.z) | ((unsigned)f2bfu(v.w) << 16);
    uint2 pk; pk.x = lo; pk.y = hi;
    *(uint2*)(out + i) = pk;
  }
}

// W[R][C] f32 -> Wt[C][R] bf16, 64x64 tiles through LDS
__global__ __launch_bounds__(256) void transpose_cvt(const float* __restrict__ W,
                                                     bf16_t* __restrict__ Wt,
                                                     int R, int C) {
  __shared__ float tile[64][65];
  const int tc = C >> 6;
  const int bc = blockIdx.x % tc;
  const int br = blockIdx.x / tc;
  #pragma unroll
  for (int p = 0; p < 16; ++p) {
    int idx = p * 256 + threadIdx.x;
    int i = idx >> 6, j = idx & 63;
    tile[i][j] = W[(size_t)(br * 64 + i) * C + bc * 64 + j];
  }
  __syncthreads();
  #pragma unroll
  for (int p = 0; p < 16; ++p) {
    int idx = p * 256 + threadIdx.x;
    int jj = idx >> 6, ii = idx & 63;
    Wt[(size_t)(bc * 64 + jj) * R + br * 64 + ii] = (bf16_t)tile[ii][jj];
  }
}

// ---------- GEMM: C[M][N] = A[M][K] * Bt[N][K]^T + bias ----------

template <bool OUT_BF16>
__global__ __launch_bounds__(256) void gemm_bt(const bf16_t* __restrict__ A,
                                               const bf16_t* __restrict__ Bt,
                                               const float* __restrict__ bias,
                                               void* __restrict__ Cout,
                                               int M, int N, int K) {
  __shared__ bf16_t As[128 * 32];
  __shared__ bf16_t Bs[128 * 32];
  const int tid = threadIdx.x;
  const int lane = tid & 63;
  const int w = tid >> 6;
  const int wr = (w >> 1) * 64;
  const int wc = (w & 1) * 64;
  const int i16 = lane & 15;
  const int g = lane >> 4;
  const int ntn = N >> 7;
  const int bm = blockIdx.x / ntn;
  const int bn = blockIdx.x % ntn;
  const bf16_t* Abase = A + (size_t)(bm * 128) * K;
  const bf16_t* Bbase = Bt + (size_t)(bn * 128) * K;

  f32x4 acc[4][4];
  #pragma unroll
  for (int m = 0; m < 4; ++m)
    #pragma unroll
    for (int n = 0; n < 4; ++n)
      acc[m][n] = (f32x4){0.f, 0.f, 0.f, 0.f};

  for (int kt = 0; kt < K; kt += 32) {
    __syncthreads();
    #pragma unroll
    for (int p = 0; p < 2; ++p) {
      int idx = p * 256 + tid;
      int row = idx >> 2, ch = idx & 3;
      gload_lds16(Abase + (size_t)row * K + kt + ch * 8, (char*)As + idx * 16);
      gload_lds16(Bbase + (size_t)row * K + kt + ch * 8, (char*)Bs + idx * 16);
    }
    __syncthreads();
    bf16x8 af[4], bq[4];
    #pragma unroll
    for (int m = 0; m < 4; ++m)
      af[m] = *(const bf16x8*)(As + (wr + m * 16 + i16) * 32 + g * 8);
    #pragma unroll
    for (int n = 0; n < 4; ++n)
      bq[n] = *(const bf16x8*)(Bs + (wc + n * 16 + i16) * 32 + g * 8);
    #pragma unroll
    for (int m = 0; m < 4; ++m)
      #pragma unroll
      for (int n = 0; n < 4; ++n)
        acc[m][n] = __builtin_amdgcn_mfma_f32_16x16x32_bf16(af[m], bq[n], acc[m][n], 0, 0, 0);
  }

  #pragma unroll
  for (int m = 0; m < 4; ++m) {
    #pragma unroll
    for (int n = 0; n < 4; ++n) {
      int col = bn * 128 + wc + n * 16 + i16;
      float bv = bias ? bias[col] : 0.f;
      #pragma unroll
      for (int r = 0; r < 4; ++r) {
        int row = bm * 128 + wr + m * 16 + g * 4 + r;
        float v = acc[m][n][r] + bv;
        if (OUT_BF16)
          ((bf16_t*)Cout)[(size_t)row * N + col] = (bf16_t)v;
        else
          ((float*)Cout)[(size_t)row * N + col] = v;
      }
    }
  }
}

// ---------- causal flash attention, 32x32 swapped form ----------
// Block = (head, 128 q rows), 4 waves x QBLK=32. KV tile = 64.
// S^T = mfma_32x32(K, Q): lane holds q = lane&31, keys crow(r,hi) = (r&3)+8*(r>>2)+4*hi
// O^T = mfma_32x32(V^T, P^T) accumulated over 4 k-steps of 16 keys.

__global__ __launch_bounds__(256) void attn_fwd(const bf16_t* __restrict__ qkv,
                                                bf16_t* __restrict__ aout) {
  __shared__ bf16_t Ks[64 * 64];
  __shared__ bf16_t Vt[64 * 64];
  const int tid = threadIdx.x;
  const int lane = tid & 63;
  const int w = tid >> 6;
  const int l31 = lane & 31;
  const int hi = lane >> 5;
  const int h = blockIdx.x & 15;
  const int qb = 31 - (blockIdx.x >> 4);   // heavy blocks first
  const int qg0 = qb * 128 + w * 32;       // wave's q base
  const int q = qg0 + l31;                 // lane's q row
  const float sc = 0.18033688011112042f;   // log2(e)/sqrt(64)

  // Q B-frags: qf[ks][j] = Q[q][ks*16 + hi*8 + j]
  bf16x8 qf[4];
  #pragma unroll
  for (int ks = 0; ks < 4; ++ks)
    qf[ks] = *(const bf16x8*)(qkv + (size_t)q * 3072 + h * 64 + ks * 16 + hi * 8);

  f32x16 ot[2];
  #pragma unroll
  for (int r = 0; r < 16; ++r) { ot[0][r] = 0.f; ot[1][r] = 0.f; }
  float m_run = -1e30f, l_run = 0.f;

  const int ntiles = 2 * qb + 2;
  for (int t = 0; t < ntiles; ++t) {
    const int kv = t * 64;
    __syncthreads();
    // K stage [64 keys][64 dh], XOR-swizzled via pre-swizzled global source
    #pragma unroll
    for (int p = 0; p < 2; ++p) {
      int idx = p * 256 + tid;
      int key = idx >> 3;
      int ch = (idx & 7) ^ (key & 7);
      gload_lds16(qkv + (size_t)(kv + key) * 3072 + 1024 + h * 64 + ch * 8,
                  (char*)Ks + idx * 16);
    }
    // V stage transposed [64 dh][64 keys], 2-way-floor swizzle
    {
      int kp = tid >> 3;
      int e = tid & 7;
      const bf16_t* vp = qkv + (size_t)(kv + 2 * kp) * 3072 + 2048 + h * 64 + e * 8;
      ushortx8 a = *(const ushortx8*)vp;
      ushortx8 b = *(const ushortx8*)(vp + 3072);
      #pragma unroll
      for (int j = 0; j < 8; ++j) {
        int dh = e * 8 + j;
        unsigned pk = (unsigned)a[j] | ((unsigned)b[j] << 16);
        int off = (dh * 128 + kp * 4) ^ ((dh & 7) << 4) ^ (((dh >> 3) & 3) << 5);
        *(unsigned*)((char*)Vt + off) = pk;
      }
    }
    __syncthreads();

    if (kv > qg0 + 31) continue;  // tile fully masked for this wave

    // QK^T (S^T): two 32-key halves
    f32x16 s0, s1;
    #pragma unroll
    for (int r = 0; r < 16; ++r) { s0[r] = 0.f; s1[r] = 0.f; }
    #pragma unroll
    for (int ks = 0; ks < 4; ++ks) {
      int off0 = (l31 * 128 + ks * 32 + hi * 16) ^ ((l31 & 7) << 4);
      bf16x8 kf0 = *(const bf16x8*)((const char*)Ks + off0);
      s0 = __builtin_amdgcn_mfma_f32_32x32x16_bf16(kf0, qf[ks], s0, 0, 0, 0);
      int r1 = 32 + l31;
      int off1 = (r1 * 128 + ks * 32 + hi * 16) ^ ((r1 & 7) << 4);
      bf16x8 kf1 = *(const bf16x8*)((const char*)Ks + off1);
      s1 = __builtin_amdgcn_mfma_f32_32x32x16_bf16(kf1, qf[ks], s1, 0, 0, 0);
    }

    // causal mask (only diagonal-adjacent tiles)
    if (kv + 63 > qg0) {
      int thr = q - kv;  // local key > thr is masked
      #pragma unroll
      for (int r = 0; r < 16; ++r) {
        int c = (r & 3) + 8 * (r >> 2) + 4 * hi;
        if (c > thr) s0[r] = -1e30f;
        if (c + 32 > thr) s1[r] = -1e30f;
      }
    }

    // row max (raw space): in-reg tree + one cross-half exchange
    float mm[8];
    #pragma unroll
    for (int r = 0; r < 8; ++r)
      mm[r] = fmaxf(fmaxf(s0[r], s0[r + 8]), fmaxf(s1[r], s1[r + 8]));
    #pragma unroll
    for (int r = 0; r < 4; ++r) mm[r] = fmaxf(mm[r], mm[r + 4]);
    float tmax = fmaxf(fmaxf(mm[0], mm[1]), fmaxf(mm[2], mm[3]));
    tmax = fmaxf(tmax, __shfl_xor(tmax, 32));

    // T13 defer-max: skip O-rescale when growth small
    if (!__all(sc * (tmax - m_run) <= 8.0f)) {
      float mnew = fmaxf(m_run, tmax);
      float alpha = __builtin_amdgcn_exp2f(sc * (m_run - mnew));
      l_run *= alpha;
      #pragma unroll
      for (int r = 0; r < 16; ++r) { ot[0][r] *= alpha; ot[1][r] *= alpha; }
      m_run = mnew;
    }

    // P = exp2(sc*s - sc*m)
    float nscm = -sc * m_run;
    #pragma unroll
    for (int r = 0; r < 16; ++r) {
      s0[r] = __builtin_amdgcn_exp2f(fmaf(s0[r], sc, nscm));
      s1[r] = __builtin_amdgcn_exp2f(fmaf(s1[r], sc, nscm));
    }
    // row sum
    f32x16 ss = s0 + s1;
    float sm[8];
    #pragma unroll
    for (int r = 0; r < 8; ++r) sm[r] = ss[r] + ss[r + 8];
    #pragma unroll
    for (int r = 0; r < 4; ++r) sm[r] = sm[r] + sm[r + 4];
    float rs = (sm[0] + sm[1]) + (sm[2] + sm[3]);
    rs += __shfl_xor(rs, 32);
    l_run += rs;

    // T12: pack P to bf16 (cvt_pk) + one half-swap -> PV B-frags
    bf16x8 pb[4];
    #pragma unroll
    for (int g2 = 0; g2 < 4; ++g2) {
      const int si = (g2 & 1) * 8;
      const f32x16& P = (g2 < 2) ? s0 : s1;
      unsigned u00 = cvt_pk_bf16(P[si + 0], P[si + 1]);
      unsigned u01 = cvt_pk_bf16(P[si + 2], P[si + 3]);
      unsigned u10 = cvt_pk_bf16(P[si + 4], P[si + 5]);
      unsigned u11 = cvt_pk_bf16(P[si + 6], P[si + 7]);
      unsigned X0 = hi ? u00 : u10;   // the half destined for the partner
      unsigned X1 = hi ? u01 : u11;
      unsigned Y0 = __shfl_xor(X0, 32);
      unsigned Y1 = __shfl_xor(X1, 32);
      unsigned S0w = hi ? u10 : u00;  // kept local half
      unsigned S1w = hi ? u11 : u01;
      uint4 f;
      f.x = hi ? Y0 : S0w;
      f.y = hi ? Y1 : S1w;
      f.z = hi ? S0w : Y0;
      f.w = hi ? S1w : Y1;
      pb[g2] = __builtin_bit_cast(bf16x8, f);
    }

    // O^T += V^T . P^T
    #pragma unroll
    for (int dt = 0; dt < 2; ++dt) {
      int dh = dt * 32 + l31;
      int swz = ((dh & 7) << 4) ^ (((dh >> 3) & 3) << 5);
      #pragma unroll
      for (int g2 = 0; g2 < 4; ++g2) {
        int off = (dh * 128 + g2 * 32 + hi * 16) ^ swz;
        bf16x8 vf = *(const bf16x8*)((const char*)Vt + off);
        ot[dt] = __builtin_amdgcn_mfma_f32_32x32x16_bf16(vf, pb[g2], ot[dt], 0, 0, 0);
      }
    }
  }

  // epilogue: lane q, dh = dt*32 + 8*rq + 4*hi + {0..3}
  float inv = 1.0f / l_run;
  #pragma unroll
  for (int dt = 0; dt < 2; ++dt) {
    #pragma unroll
    for (int rq = 0; rq < 4; ++rq) {
      unsigned lo = cvt_pk_bf16(ot[dt][4 * rq + 0] * inv, ot[dt][4 * rq + 1] * inv);
      unsigned hi2 = cvt_pk_bf16(ot[dt][4 * rq + 2] * inv, ot[dt][4 * rq + 3] * inv);
      uint2 pk2; pk2.x = lo; pk2.y = hi2;
      *(uint2*)(aout + (size_t)q * 1024 + h * 64 + dt * 32 + 8 * rq + 4 * hi) = pk2;
    }
  }
}

// ---------- launch ----------

extern "C" void kernel_launch(void* const* d_in, const int* in_sizes, int n_in,
                              void* d_out, int out_size, void* d_ws, size_t ws_size,
                              hipStream_t stream) {
  const float* x     = (const float*)d_in[0];
  const float* w_qkv = (const float*)d_in[1];
  const float* b_qkv = (const float*)d_in[2];
  const float* w_o   = (const float*)d_in[3];
  const float* b_o   = (const float*)d_in[4];

  char* ws = (char*)d_ws;
  bf16_t* xh    = (bf16_t*)(ws);                          //  8 MiB
  bf16_t* wqkvT = (bf16_t*)(ws + 8388608);                //  6 MiB
  bf16_t* woT   = (bf16_t*)(ws + 14680064);               //  2 MiB
  bf16_t* qkv   = (bf16_t*)(ws + 16777216);               // 24 MiB
  bf16_t* aout  = (bf16_t*)(ws + 41943040);               //  8 MiB

  cvt_f32_bf16<<<(SEQ_LEN * D_MODEL) / 1024, 256, 0, stream>>>(x, xh, SEQ_LEN * D_MODEL);
  transpose_cvt<<<(1024 / 64) * (3072 / 64), 256, 0, stream>>>(w_qkv, wqkvT, 1024, 3072);
  transpose_cvt<<<(1024 / 64) * (1024 / 64), 256, 0, stream>>>(w_o, woT, 1024, 1024);

  gemm_bt<true><<<(4096 / 128) * (3072 / 128), 256, 0, stream>>>(
      xh, wqkvT, b_qkv, (void*)qkv, 4096, 3072, 1024);

  attn_fwd<<<N_HEAD * (SEQ_LEN / 128), 256, 0, stream>>>(qkv, aout);

  gemm_bt<false><<<(4096 / 128) * (1024 / 128), 256, 0, stream>>>(
      aout, woT, b_o, d_out, 4096, 1024, 1024);
}

// Round 3
// 181.804 us; speedup vs baseline: 1.4607x; 1.0617x over previous
//
#include <hip/hip_runtime.h>
#include <hip/hip_bf16.h>
#include <stdint.h>

typedef __bf16 bf16_t;
typedef __bf16 bf16x8 __attribute__((ext_vector_type(8)));
typedef float f32x4 __attribute__((ext_vector_type(4)));
typedef float f32x16 __attribute__((ext_vector_type(16)));

#define SEQ_LEN 4096
#define D_MODEL 1024
#define N_HEAD 16

// ---------- helpers ----------

__device__ __forceinline__ void gload_lds16(const void* g, void* lds) {
  __builtin_amdgcn_global_load_lds(
      (__attribute__((address_space(1))) void*)(g),
      (__attribute__((address_space(3))) void*)(lds), 16, 0, 0);
}

__device__ __forceinline__ unsigned short f2bfu(float f) {
  __bf16 h = (__bf16)f;
  return __builtin_bit_cast(unsigned short, h);
}

__device__ __forceinline__ unsigned cvt_pk_bf16(float a, float b) {
  unsigned r;
  asm("v_cvt_pk_bf16_f32 %0, %1, %2" : "=v"(r) : "v"(a), "v"(b));
  return r;  // lo = bf16(a), hi = bf16(b)
}

// ---------- conversion kernels ----------

__global__ __launch_bounds__(256) void cvt_f32_bf16(const float* __restrict__ in,
                                                    bf16_t* __restrict__ out, int n) {
  int i = (blockIdx.x * 256 + threadIdx.x) * 4;
  if (i < n) {
    float4 v = *(const float4*)(in + i);
    unsigned int lo = (unsigned)f2bfu(v.x) | ((unsigned)f2bfu(v.y) << 16);
    unsigned int hi = (unsigned)f2bfu(v.z) | ((unsigned)f2bfu(v.w) << 16);
    uint2 pk; pk.x = lo; pk.y = hi;
    *(uint2*)(out + i) = pk;
  }
}

// W[R][C] f32 -> Wt[C][R] bf16, 64x64 tiles through LDS
__global__ __launch_bounds__(256) void transpose_cvt(const float* __restrict__ W,
                                                     bf16_t* __restrict__ Wt,
                                                     int R, int C) {
  __shared__ float tile[64][65];
  const int tc = C >> 6;
  const int bc = blockIdx.x % tc;
  const int br = blockIdx.x / tc;
  #pragma unroll
  for (int p = 0; p < 16; ++p) {
    int idx = p * 256 + threadIdx.x;
    int i = idx >> 6, j = idx & 63;
    tile[i][j] = W[(size_t)(br * 64 + i) * C + bc * 64 + j];
  }
  __syncthreads();
  #pragma unroll
  for (int p = 0; p < 16; ++p) {
    int idx = p * 256 + threadIdx.x;
    int jj = idx >> 6, ii = idx & 63;
    Wt[(size_t)(bc * 64 + jj) * R + br * 64 + ii] = (bf16_t)tile[ii][jj];
  }
}

// ---------- GEMM: C[M][N] = A[M][K] * Bt[N][K]^T + bias ----------
// VSPLIT: columns >= 2048 (the V third of QKV) are written TRANSPOSED to
// vtout[col-2048][row] (packed 8B stores) instead of row-major Cout.

template <bool OUT_BF16, bool VSPLIT>
__global__ __launch_bounds__(256) void gemm_bt(const bf16_t* __restrict__ A,
                                               const bf16_t* __restrict__ Bt,
                                               const float* __restrict__ bias,
                                               void* __restrict__ Cout,
                                               bf16_t* __restrict__ vtout,
                                               int M, int N, int K) {
  __shared__ bf16_t As[128 * 32];
  __shared__ bf16_t Bs[128 * 32];
  const int tid = threadIdx.x;
  const int lane = tid & 63;
  const int w = tid >> 6;
  const int wr = (w >> 1) * 64;
  const int wc = (w & 1) * 64;
  const int i16 = lane & 15;
  const int g = lane >> 4;
  const int ntn = N >> 7;
  const int bm = blockIdx.x / ntn;
  const int bn = blockIdx.x % ntn;
  const bf16_t* Abase = A + (size_t)(bm * 128) * K;
  const bf16_t* Bbase = Bt + (size_t)(bn * 128) * K;

  f32x4 acc[4][4];
  #pragma unroll
  for (int m = 0; m < 4; ++m)
    #pragma unroll
    for (int n = 0; n < 4; ++n)
      acc[m][n] = (f32x4){0.f, 0.f, 0.f, 0.f};

  for (int kt = 0; kt < K; kt += 32) {
    __syncthreads();
    #pragma unroll
    for (int p = 0; p < 2; ++p) {
      int idx = p * 256 + tid;
      int row = idx >> 2, ch = idx & 3;
      gload_lds16(Abase + (size_t)row * K + kt + ch * 8, (char*)As + idx * 16);
      gload_lds16(Bbase + (size_t)row * K + kt + ch * 8, (char*)Bs + idx * 16);
    }
    __syncthreads();
    bf16x8 af[4], bq[4];
    #pragma unroll
    for (int m = 0; m < 4; ++m)
      af[m] = *(const bf16x8*)(As + (wr + m * 16 + i16) * 32 + g * 8);
    #pragma unroll
    for (int n = 0; n < 4; ++n)
      bq[n] = *(const bf16x8*)(Bs + (wc + n * 16 + i16) * 32 + g * 8);
    #pragma unroll
    for (int m = 0; m < 4; ++m)
      #pragma unroll
      for (int n = 0; n < 4; ++n)
        acc[m][n] = __builtin_amdgcn_mfma_f32_16x16x32_bf16(af[m], bq[n], acc[m][n], 0, 0, 0);
  }

  #pragma unroll
  for (int m = 0; m < 4; ++m) {
    #pragma unroll
    for (int n = 0; n < 4; ++n) {
      int col = bn * 128 + wc + n * 16 + i16;
      float bv = bias ? bias[col] : 0.f;
      int row0 = bm * 128 + wr + m * 16 + g * 4;
      if (VSPLIT && col >= 2048) {
        uint2 pk;
        pk.x = cvt_pk_bf16(acc[m][n][0] + bv, acc[m][n][1] + bv);
        pk.y = cvt_pk_bf16(acc[m][n][2] + bv, acc[m][n][3] + bv);
        *(uint2*)(vtout + (size_t)(col - 2048) * 4096 + row0) = pk;
      } else {
        #pragma unroll
        for (int r = 0; r < 4; ++r) {
          float v = acc[m][n][r] + bv;
          if (OUT_BF16)
            ((bf16_t*)Cout)[(size_t)(row0 + r) * N + col] = (bf16_t)v;
          else
            ((float*)Cout)[(size_t)(row0 + r) * N + col] = v;
        }
      }
    }
  }
}

// ---------- causal flash attention, 32x32 swapped form, pipelined ----------
// Block = (head, 128 q rows), 4 waves x QBLK=32. KV tile = 64.
// K and V^T both staged via global_load_lds with pre-swizzled source;
// double-buffered LDS, ONE barrier per tile (stage t+1 overlaps compute t).

__global__ __launch_bounds__(256) void attn_fwd(const bf16_t* __restrict__ qkv,
                                                const bf16_t* __restrict__ vt,
                                                bf16_t* __restrict__ aout) {
  __shared__ bf16_t Ks[2][64 * 64];
  __shared__ bf16_t Vs[2][64 * 64];
  const int tid = threadIdx.x;
  const int lane = tid & 63;
  const int w = tid >> 6;
  const int l31 = lane & 31;
  const int hi = lane >> 5;
  const int h = blockIdx.x & 15;
  const int qb = 31 - (blockIdx.x >> 4);   // heavy blocks first
  const int qg0 = qb * 128 + w * 32;
  const int q = qg0 + l31;
  const float sc = 0.18033688011112042f;   // log2(e)/sqrt(64)

  // per-thread staging source pattern (same for K and V)
  const int srr0 = tid >> 3;                     // row for p=0 (p=1: +32)
  const int sch0 = (tid & 7) ^ (srr0 & 7);
  const int sch1 = (tid & 7) ^ ((srr0 + 32) & 7);

#define STAGE(buf, kv)                                                          \
  {                                                                             \
    gload_lds16(qkv + (size_t)((kv) + srr0) * 3072 + 1024 + h * 64 + sch0 * 8,  \
                (char*)Ks[buf] + tid * 16);                                     \
    gload_lds16(vt + (size_t)(h * 64 + srr0) * 4096 + (kv) + sch0 * 8,          \
                (char*)Vs[buf] + tid * 16);                                     \
    gload_lds16(qkv + (size_t)((kv) + srr0 + 32) * 3072 + 1024 + h * 64 + sch1 * 8, \
                (char*)Ks[buf] + 4096 + tid * 16);                              \
    gload_lds16(vt + (size_t)(h * 64 + srr0 + 32) * 4096 + (kv) + sch1 * 8,     \
                (char*)Vs[buf] + 4096 + tid * 16);                              \
  }

  // Q B-frags: qf[ks][j] = Q[q][ks*16 + hi*8 + j]
  bf16x8 qf[4];
  #pragma unroll
  for (int ks = 0; ks < 4; ++ks)
    qf[ks] = *(const bf16x8*)(qkv + (size_t)q * 3072 + h * 64 + ks * 16 + hi * 8);

  f32x16 ot[2];
  #pragma unroll
  for (int r = 0; r < 16; ++r) { ot[0][r] = 0.f; ot[1][r] = 0.f; }
  float m_run = -1e30f, l_run = 0.f;

  const int ntiles = 2 * qb + 2;
  STAGE(0, 0);
  __syncthreads();
  int cur = 0;

  for (int t = 0; t < ntiles; ++t) {
    const int kv = t * 64;
    if (t + 1 < ntiles) STAGE(cur ^ 1, (t + 1) * 64);

    if (kv <= qg0 + 31) {
      const bf16_t* Kc = Ks[cur];
      const bf16_t* Vc = Vs[cur];

      // QK^T (S^T): two 32-key halves
      f32x16 s0, s1;
      #pragma unroll
      for (int r = 0; r < 16; ++r) { s0[r] = 0.f; s1[r] = 0.f; }
      __builtin_amdgcn_s_setprio(1);
      #pragma unroll
      for (int ks = 0; ks < 4; ++ks) {
        int off0 = (l31 * 128 + ks * 32 + hi * 16) ^ ((l31 & 7) << 4);
        bf16x8 kf0 = *(const bf16x8*)((const char*)Kc + off0);
        s0 = __builtin_amdgcn_mfma_f32_32x32x16_bf16(kf0, qf[ks], s0, 0, 0, 0);
        int r1 = 32 + l31;
        int off1 = (r1 * 128 + ks * 32 + hi * 16) ^ ((r1 & 7) << 4);
        bf16x8 kf1 = *(const bf16x8*)((const char*)Kc + off1);
        s1 = __builtin_amdgcn_mfma_f32_32x32x16_bf16(kf1, qf[ks], s1, 0, 0, 0);
      }
      __builtin_amdgcn_s_setprio(0);

      // causal mask (diagonal-adjacent tiles only)
      if (kv + 63 > qg0) {
        int thr = q - kv;
        #pragma unroll
        for (int r = 0; r < 16; ++r) {
          int c = (r & 3) + 8 * (r >> 2) + 4 * hi;
          if (c > thr) s0[r] = -1e30f;
          if (c + 32 > thr) s1[r] = -1e30f;
        }
      }

      // row max: in-reg tree + one cross-half exchange
      float mm[8];
      #pragma unroll
      for (int r = 0; r < 8; ++r)
        mm[r] = fmaxf(fmaxf(s0[r], s0[r + 8]), fmaxf(s1[r], s1[r + 8]));
      #pragma unroll
      for (int r = 0; r < 4; ++r) mm[r] = fmaxf(mm[r], mm[r + 4]);
      float tmax = fmaxf(fmaxf(mm[0], mm[1]), fmaxf(mm[2], mm[3]));
      tmax = fmaxf(tmax, __shfl_xor(tmax, 32));

      // T13 defer-max
      if (!__all(sc * (tmax - m_run) <= 8.0f)) {
        float mnew = fmaxf(m_run, tmax);
        float alpha = __builtin_amdgcn_exp2f(sc * (m_run - mnew));
        l_run *= alpha;
        #pragma unroll
        for (int r = 0; r < 16; ++r) { ot[0][r] *= alpha; ot[1][r] *= alpha; }
        m_run = mnew;
      }

      // P = exp2(sc*s - sc*m)
      float nscm = -sc * m_run;
      #pragma unroll
      for (int r = 0; r < 16; ++r) {
        s0[r] = __builtin_amdgcn_exp2f(fmaf(s0[r], sc, nscm));
        s1[r] = __builtin_amdgcn_exp2f(fmaf(s1[r], sc, nscm));
      }
      // row sum
      f32x16 ss = s0 + s1;
      float sm[8];
      #pragma unroll
      for (int r = 0; r < 8; ++r) sm[r] = ss[r] + ss[r + 8];
      #pragma unroll
      for (int r = 0; r < 4; ++r) sm[r] = sm[r] + sm[r + 4];
      float rs = (sm[0] + sm[1]) + (sm[2] + sm[3]);
      rs += __shfl_xor(rs, 32);
      l_run += rs;

      // T12: pack P to bf16 + one half-swap -> PV B-frags
      bf16x8 pb[4];
      #pragma unroll
      for (int g2 = 0; g2 < 4; ++g2) {
        const int si = (g2 & 1) * 8;
        const f32x16& P = (g2 < 2) ? s0 : s1;
        unsigned u00 = cvt_pk_bf16(P[si + 0], P[si + 1]);
        unsigned u01 = cvt_pk_bf16(P[si + 2], P[si + 3]);
        unsigned u10 = cvt_pk_bf16(P[si + 4], P[si + 5]);
        unsigned u11 = cvt_pk_bf16(P[si + 6], P[si + 7]);
        unsigned X0 = hi ? u00 : u10;
        unsigned X1 = hi ? u01 : u11;
        unsigned Y0 = __shfl_xor(X0, 32);
        unsigned Y1 = __shfl_xor(X1, 32);
        unsigned S0w = hi ? u10 : u00;
        unsigned S1w = hi ? u11 : u01;
        uint4 f;
        f.x = hi ? Y0 : S0w;
        f.y = hi ? Y1 : S1w;
        f.z = hi ? S0w : Y0;
        f.w = hi ? S1w : Y1;
        pb[g2] = __builtin_bit_cast(bf16x8, f);
      }

      // O^T += V^T . P^T
      __builtin_amdgcn_s_setprio(1);
      #pragma unroll
      for (int dt = 0; dt < 2; ++dt) {
        int dh = dt * 32 + l31;
        int swz = (dh & 7) << 4;
        #pragma unroll
        for (int g2 = 0; g2 < 4; ++g2) {
          int off = (dh * 128 + g2 * 32 + hi * 16) ^ swz;
          bf16x8 vf = *(const bf16x8*)((const char*)Vc + off);
          ot[dt] = __builtin_amdgcn_mfma_f32_32x32x16_bf16(vf, pb[g2], ot[dt], 0, 0, 0);
        }
      }
      __builtin_amdgcn_s_setprio(0);
    }

    __syncthreads();   // drains this iter's prefetch (overlapped with compute)
    cur ^= 1;
  }
#undef STAGE

  // epilogue: lane q, dh = dt*32 + 8*rq + 4*hi + {0..3}
  float inv = 1.0f / l_run;
  #pragma unroll
  for (int dt = 0; dt < 2; ++dt) {
    #pragma unroll
    for (int rq = 0; rq < 4; ++rq) {
      unsigned lo = cvt_pk_bf16(ot[dt][4 * rq + 0] * inv, ot[dt][4 * rq + 1] * inv);
      unsigned hi2 = cvt_pk_bf16(ot[dt][4 * rq + 2] * inv, ot[dt][4 * rq + 3] * inv);
      uint2 pk2; pk2.x = lo; pk2.y = hi2;
      *(uint2*)(aout + (size_t)q * 1024 + h * 64 + dt * 32 + 8 * rq + 4 * hi) = pk2;
    }
  }
}

// ---------- launch ----------

extern "C" void kernel_launch(void* const* d_in, const int* in_sizes, int n_in,
                              void* d_out, int out_size, void* d_ws, size_t ws_size,
                              hipStream_t stream) {
  const float* x     = (const float*)d_in[0];
  const float* w_qkv = (const float*)d_in[1];
  const float* b_qkv = (const float*)d_in[2];
  const float* w_o   = (const float*)d_in[3];
  const float* b_o   = (const float*)d_in[4];

  char* ws = (char*)d_ws;
  bf16_t* xh    = (bf16_t*)(ws);                          //  8 MiB
  bf16_t* wqkvT = (bf16_t*)(ws + 8388608);                //  6 MiB
  bf16_t* woT   = (bf16_t*)(ws + 14680064);               //  2 MiB
  bf16_t* qkv   = (bf16_t*)(ws + 16777216);               // 24 MiB (Q,K thirds used)
  bf16_t* aout  = (bf16_t*)(ws + 41943040);               //  8 MiB
  bf16_t* vtg   = (bf16_t*)(ws + 50331648);               //  8 MiB  V^T [1024][4096]

  cvt_f32_bf16<<<(SEQ_LEN * D_MODEL) / 1024, 256, 0, stream>>>(x, xh, SEQ_LEN * D_MODEL);
  transpose_cvt<<<(1024 / 64) * (3072 / 64), 256, 0, stream>>>(w_qkv, wqkvT, 1024, 3072);
  transpose_cvt<<<(1024 / 64) * (1024 / 64), 256, 0, stream>>>(w_o, woT, 1024, 1024);

  gemm_bt<true, true><<<(4096 / 128) * (3072 / 128), 256, 0, stream>>>(
      xh, wqkvT, b_qkv, (void*)qkv, vtg, 4096, 3072, 1024);

  attn_fwd<<<N_HEAD * (SEQ_LEN / 128), 256, 0, stream>>>(qkv, vtg, aout);

  gemm_bt<false, false><<<(4096 / 128) * (1024 / 128), 256, 0, stream>>>(
      aout, woT, b_o, d_out, nullptr, 4096, 1024, 1024);
}